// Round 7
// baseline (163.372 us; speedup 1.0000x reference)
//
#include <hip/hip_runtime.h>

typedef short bf16x8 __attribute__((ext_vector_type(8)));
typedef short bf16x4 __attribute__((ext_vector_type(4)));
typedef float f32x4 __attribute__((ext_vector_type(4)));
typedef unsigned short u16;
typedef u16 u16x8 __attribute__((ext_vector_type(8)));
typedef u16 u16x4 __attribute__((ext_vector_type(4)));

#define L_ 2048
#define D_ 512
#define H_ 8
#define DH_ 64
#define DIN 508

static __device__ __forceinline__ u16 f2b(float f){
  unsigned u = __builtin_bit_cast(unsigned, f);
  unsigned r = u + 0x7fffu + ((u >> 16) & 1u);   // round-to-nearest-even
  return (u16)(r >> 16);
}
static __device__ __forceinline__ float b2f(u16 u){
  unsigned x = ((unsigned)u) << 16;
  return __builtin_bit_cast(float, x);
}
static __device__ __forceinline__ bf16x8 asbf(u16x8 v){
  return __builtin_bit_cast(bf16x8, v);
}
static __device__ __forceinline__ bf16x4 asbf4(u16x4 v){
  return __builtin_bit_cast(bf16x4, v);
}
#define MFMA16(a,b,c) __builtin_amdgcn_mfma_f32_16x16x32_bf16(a,b,c,0,0,0)

// K=16 bf16 MFMA (legacy CDNA2+ instruction, present on gfx950)
#if __has_builtin(__builtin_amdgcn_mfma_f32_16x16x16bf16_1k)
static __device__ __forceinline__ f32x4 MFMA16K16(bf16x4 a, bf16x4 b, f32x4 c){
  return __builtin_amdgcn_mfma_f32_16x16x16bf16_1k(a, b, c, 0, 0, 0);
}
#elif __has_builtin(__builtin_amdgcn_mfma_f32_16x16x16_bf16)
static __device__ __forceinline__ f32x4 MFMA16K16(bf16x4 a, bf16x4 b, f32x4 c){
  return __builtin_amdgcn_mfma_f32_16x16x16_bf16(a, b, c, 0, 0, 0);
}
#else
static __device__ __forceinline__ f32x4 MFMA16K16(bf16x4 a, bf16x4 b, f32x4 c){
  f32x4 d;
  asm volatile("v_mfma_f32_16x16x16_bf16 %0, %1, %2, %3\n\ts_nop 7"
               : "=&v"(d) : "v"(a), "v"(b), "v"(c));
  return d;
}
#endif

// ---------------------------------------------------------------------------
// Kernel 0: one-shot fp32 -> bf16 conversion (+ zero-pad X).
// ---------------------------------------------------------------------------
__global__ __launch_bounds__(512) void cvt_kernel(
    const float* __restrict__ inp, const float* __restrict__ Wq,
    const float* __restrict__ Wk, const float* __restrict__ Wv,
    u16* __restrict__ Xb, u16* __restrict__ Wb)
{
  const int tid = blockIdx.x*512 + threadIdx.x;
  if (tid < 262144) {                       // X part: 4096*512/8 threads
    const int idx8 = tid*8;
    const int row = idx8 >> 9, col = idx8 & 511;
    u16x8 o;
    #pragma unroll
    for (int e=0;e<8;++e){
      const int c = col+e;
      const float v = (c>=2 && c<510) ? inp[(size_t)row*DIN + (c-2)] : 0.f;
      o[e] = f2b(v);
    }
    *(u16x8*)&Xb[idx8] = o;
  } else {                                  // W part: 1536*512/8 threads
    const int idx8 = (tid - 262144)*8;
    const int row = idx8 >> 9, col = idx8 & 511;
    const float* __restrict__ W = (row < 512) ? Wq : (row < 1024) ? Wk : Wv;
    const float* p = &W[(size_t)(row & 511)*D_ + col];
    u16x8 o;
    #pragma unroll
    for (int e=0;e<8;++e) o[e] = f2b(p[e]);
    *(u16x8*)&Wb[idx8] = o;
  }
}

// ---------------------------------------------------------------------------
// Kernel 1: QKV projection, pure-bf16 GEMM.  C[i][n] = sum_k Xb[i][k]*Wb[n][k]
// Q,K stored bf16 as [bh][l][dh]; V stored TRANSPOSED bf16 as [bh][dh][l].
// ---------------------------------------------------------------------------
__global__ __launch_bounds__(512) void proj_kernel(
    const u16* __restrict__ Xb, const u16* __restrict__ Wb,
    u16* __restrict__ Qg, u16* __restrict__ Kg, u16* __restrict__ Vt)
{
  __shared__ u16 Xl[128*72];   // stride 72 u16 = 36dw (== 4 mod 32): conflict-free
  __shared__ u16 Wl[128*72];
  const int t = threadIdx.x;
  const int lane = t & 63, wid = t >> 6;
  const int wr = wid >> 2, wc = wid & 3;          // 2x4 wave grid -> 64x32 per wave
  const int i0 = blockIdx.x * 128;
  const int j0 = blockIdx.y * 128;                // 0..1535
  const int mat = j0 >> 9;                        // 0:Q 1:K 2:V
  const int srow = t >> 3, sc8 = (t & 7) * 8;

  f32x4 acc[4][2];
  #pragma unroll
  for (int a=0;a<4;++a){
    #pragma unroll
    for (int bq=0;bq<2;++bq){ f32x4 z = {0.f,0.f,0.f,0.f}; acc[a][bq] = z; }
  }

  u16x8 xa0 = *(const u16x8*)&Xb[(size_t)(i0+srow)*D_ + sc8];
  u16x8 xa1 = *(const u16x8*)&Xb[(size_t)(i0+64+srow)*D_ + sc8];
  u16x8 wa0 = *(const u16x8*)&Wb[(size_t)(j0+srow)*D_ + sc8];
  u16x8 wa1 = *(const u16x8*)&Wb[(size_t)(j0+64+srow)*D_ + sc8];

  for (int kt=0; kt<8; ++kt){
    __syncthreads();
    *(u16x8*)&Xl[srow*72 + sc8] = xa0;
    *(u16x8*)&Xl[(64+srow)*72 + sc8] = xa1;
    *(u16x8*)&Wl[srow*72 + sc8] = wa0;
    *(u16x8*)&Wl[(64+srow)*72 + sc8] = wa1;
    __syncthreads();
    if (kt < 7){
      const int k1 = (kt+1)*64;
      xa0 = *(const u16x8*)&Xb[(size_t)(i0+srow)*D_ + k1 + sc8];
      xa1 = *(const u16x8*)&Xb[(size_t)(i0+64+srow)*D_ + k1 + sc8];
      wa0 = *(const u16x8*)&Wb[(size_t)(j0+srow)*D_ + k1 + sc8];
      wa1 = *(const u16x8*)&Wb[(size_t)(j0+64+srow)*D_ + k1 + sc8];
    }
    #pragma unroll
    for (int ks=0; ks<2; ++ks){
      const int ko = ks*32 + (lane>>4)*8;
      bf16x8 af[4], bfr[2];
      #pragma unroll
      for (int fm=0; fm<4; ++fm)
        af[fm] = *(const bf16x8*)&Xl[(wr*64 + fm*16 + (lane&15))*72 + ko];
      #pragma unroll
      for (int fn=0; fn<2; ++fn)
        bfr[fn] = *(const bf16x8*)&Wl[(wc*32 + fn*16 + (lane&15))*72 + ko];
      #pragma unroll
      for (int fm=0; fm<4; ++fm){
        #pragma unroll
        for (int fn=0; fn<2; ++fn)
          acc[fm][fn] = MFMA16(af[fm], bfr[fn], acc[fm][fn]);
      }
    }
  }
  #pragma unroll
  for (int fm=0; fm<4; ++fm){
    const int ibase = i0 + wr*64 + fm*16 + (lane>>4)*4;
    const int b = ibase >> 11;
    const int li = ibase & (L_-1);
    #pragma unroll
    for (int fn=0; fn<2; ++fn){
      const int n = j0 + wc*32 + fn*16 + (lane&15);
      const int h = (n>>6) & 7;
      const int dh = n & 63;
      if (mat == 2){
        u16x4 pk;
        #pragma unroll
        for (int r=0;r<4;++r) pk[r] = f2b(acc[fm][fn][r]);
        *(u16x4*)&Vt[((size_t)(b*H_+h)*DH_ + dh)*L_ + li] = pk;   // contiguous in l
      } else {
        u16* dst = ((mat==0)? Qg : Kg) + ((size_t)(b*H_+h)*L_ + li)*DH_ + dh;
        #pragma unroll
        for (int r=0;r<4;++r) dst[(size_t)r*DH_] = f2b(acc[fm][fn][r]);
      }
    }
  }
}

// ---------------------------------------------------------------------------
// Kernel 2: attention, two-pass over K (recompute QK^T), m-slice PV.
// Block = 32 q-rows of one (b,h), 512 thr = 8 waves.
// Pass A: ZERO barriers — direct-global K fragments (L2-resident).
// Pass B: ONE barrier/tile. Each wave owns a 16-m slice: its S^T exp values
//   are ALREADY in the K=16 MFMA A-frag layout (k=(lane>>4)*4+j), so PV is
//   8 register-only mfma_16x16x16 per tile with V-frags gathered from
//   L2-resident V^T. Pt (dbuf) exists only to feed the dense coalesced
//   nontemporal attn store. Cross-wave O-reduction happens ONCE at the end.
// ---------------------------------------------------------------------------
__global__ __launch_bounds__(512, 4) void attn_kernel(
    const u16* __restrict__ Qg, const u16* __restrict__ Kg,
    const u16* __restrict__ Vt, float* __restrict__ attn, float* __restrict__ Og)
{
  __shared__ char smem[35968];
  u16*   Pt0    = (u16*)smem;                    // [32*136] = 8704 B
  u16*   Pt1    = (u16*)(smem + 8704);           // [32*136]
  float* red    = (float*)smem;                  // [4][32*68] = 34816 B (aliases Pt, used after loop)
  float* rsp    = (float*)(smem + 34816);        // [8][32]
  float* inv_rs = (float*)(smem + 35840);        // [32]

  const int t = threadIdx.x, lane = t & 63, wid = t >> 6;
  const int lane15 = lane & 15, g = lane >> 4;
  // XCD swizzle: xcd = lin&7; bh = xcd + 8*(idx&1); q0 = (idx>>1)*32
  const int lin = blockIdx.x;
  const int idx = lin >> 3;
  const int bh = (lin & 7) + 8*(idx & 1);
  const int q0 = (idx >> 1) * 32;
  const u16* Qp = Qg + ((size_t)bh*L_ + q0)*DH_;
  const u16* Kp = Kg + (size_t)bh*L_*DH_;
  const u16* Vp = Vt + (size_t)bh*DH_*L_;

  // Q fragments: rows q = qi*16 + lane15, cols k = ks*32 + g*8
  bf16x8 qf[2][2];
  #pragma unroll
  for (int qi=0;qi<2;++qi){
    #pragma unroll
    for (int ks=0;ks<2;++ks)
      qf[qi][ks] = *(const bf16x8*)&Qp[(size_t)(qi*16 + lane15)*DH_ + ks*32 + g*8];
  }

  const int g4 = g*8;
  const int mrow = wid*16 + lane15;        // this wave's K rows (m slice)

  // ---------------- pass A: row sums of exp(S), no LDS, no barriers --------
  float racc0 = 0.f, racc1 = 0.f;
  {
    u16x8 nk0 = *(const u16x8*)&Kp[(size_t)mrow*DH_ + g4];
    u16x8 nk1 = *(const u16x8*)&Kp[(size_t)mrow*DH_ + 32 + g4];
    for (int kt=0; kt<16; ++kt){
      bf16x8 kf0 = asbf(nk0), kf1 = asbf(nk1);
      if (kt < 15){
        nk0 = *(const u16x8*)&Kp[(size_t)((kt+1)*128 + mrow)*DH_ + g4];
        nk1 = *(const u16x8*)&Kp[(size_t)((kt+1)*128 + mrow)*DH_ + 32 + g4];
      }
      f32x4 s0 = {0.f,0.f,0.f,0.f}, s1 = {0.f,0.f,0.f,0.f};
      s0 = MFMA16(kf0, qf[0][0], s0); s0 = MFMA16(kf1, qf[0][1], s0);
      s1 = MFMA16(kf0, qf[1][0], s1); s1 = MFMA16(kf1, qf[1][1], s1);
      #pragma unroll
      for (int r=0;r<4;++r){
        racc0 += __expf(s0[r]*0.125f);
        racc1 += __expf(s1[r]*0.125f);
      }
    }
  }
  racc0 += __shfl_xor(racc0, 16); racc0 += __shfl_xor(racc0, 32);
  racc1 += __shfl_xor(racc1, 16); racc1 += __shfl_xor(racc1, 32);
  if (lane < 16){ rsp[wid*32 + lane] = racc0; rsp[wid*32 + 16 + lane] = racc1; }
  __syncthreads();
  if (t < 32){
    float s = 0.f;
    #pragma unroll
    for (int w=0;w<8;++w) s += rsp[w*32 + t];
    inv_rs[t] = 1.f/s;
  }
  __syncthreads();

  // ---------------- pass B: 1 barrier/tile; m-slice PV ----------------
  f32x4 o[2][4];
  #pragma unroll
  for (int qi=0;qi<2;++qi){
    #pragma unroll
    for (int db=0;db<4;++db){ f32x4 z = {0.f,0.f,0.f,0.f}; o[qi][db] = z; }
  }
  const int sr = t >> 4;                    // store: row in tile (0..31)
  const int sc4 = (t & 15) * 4;             // store: col chunk
  float* abase = attn + ((size_t)bh*L_ + q0 + sr)*L_ + sc4;
  const float sinv = inv_rs[sr];

  u16x8 k0 = *(const u16x8*)&Kp[(size_t)mrow*DH_ + g4];
  u16x8 k1 = *(const u16x8*)&Kp[(size_t)mrow*DH_ + 32 + g4];
  for (int kt=0; kt<16; ++kt){
    u16* Ptc = (kt & 1) ? Pt1 : Pt0;
    // V fragments for this tile (direct from L2-resident V^T):
    // Y[d=lane15][k=g*4+j] = V[m0w + g*4 + j][db*16 + lane15]
    const int m0w = kt*128 + wid*16 + g*4;
    bf16x4 vf0 = *(const bf16x4*)&Vp[(size_t)( 0 + lane15)*L_ + m0w];
    bf16x4 vf1 = *(const bf16x4*)&Vp[(size_t)(16 + lane15)*L_ + m0w];
    bf16x4 vf2 = *(const bf16x4*)&Vp[(size_t)(32 + lane15)*L_ + m0w];
    bf16x4 vf3 = *(const bf16x4*)&Vp[(size_t)(48 + lane15)*L_ + m0w];
    // S^T from prefetched K regs
    f32x4 s0 = {0.f,0.f,0.f,0.f}, s1 = {0.f,0.f,0.f,0.f};
    s0 = MFMA16(asbf(k0), qf[0][0], s0); s0 = MFMA16(asbf(k1), qf[0][1], s0);
    s1 = MFMA16(asbf(k0), qf[1][0], s1); s1 = MFMA16(asbf(k1), qf[1][1], s1);
    if (kt < 15){
      k0 = *(const u16x8*)&Kp[(size_t)((kt+1)*128 + mrow)*DH_ + g4];
      k1 = *(const u16x8*)&Kp[(size_t)((kt+1)*128 + mrow)*DH_ + 32 + g4];
    }
    // exp -> bf16: p0/p1 are BOTH the attn values and the PV A-fragments
    u16x4 p0, p1;
    p0[0] = f2b(__expf(s0[0]*0.125f)); p0[1] = f2b(__expf(s0[1]*0.125f));
    p0[2] = f2b(__expf(s0[2]*0.125f)); p0[3] = f2b(__expf(s0[3]*0.125f));
    p1[0] = f2b(__expf(s1[0]*0.125f)); p1[1] = f2b(__expf(s1[1]*0.125f));
    p1[2] = f2b(__expf(s1[2]*0.125f)); p1[3] = f2b(__expf(s1[3]*0.125f));
    *(u16x4*)&Ptc[lane15*136 + wid*16 + g*4] = p0;
    *(u16x4*)&Ptc[(16 + lane15)*136 + wid*16 + g*4] = p1;
    // PV: register A-frags x direct-global B-frags (no LDS dependency)
    o[0][0] = MFMA16K16(asbf4(p0), vf0, o[0][0]);
    o[1][0] = MFMA16K16(asbf4(p1), vf0, o[1][0]);
    o[0][1] = MFMA16K16(asbf4(p0), vf1, o[0][1]);
    o[1][1] = MFMA16K16(asbf4(p1), vf1, o[1][1]);
    o[0][2] = MFMA16K16(asbf4(p0), vf2, o[0][2]);
    o[1][2] = MFMA16K16(asbf4(p1), vf2, o[1][2]);
    o[0][3] = MFMA16K16(asbf4(p0), vf3, o[0][3]);
    o[1][3] = MFMA16K16(asbf4(p1), vf3, o[1][3]);
    __syncthreads();                         // Ptc complete
    // dense normalized attn store: 16 lanes = 256 B contiguous per instr
    {
      const u16x4 pva = *(const u16x4*)&Ptc[sr*136 + sc4];
      const u16x4 pvb = *(const u16x4*)&Ptc[sr*136 + 64 + sc4];
      f32x4 w0, w1;
      w0[0]=b2f(pva[0])*sinv; w0[1]=b2f(pva[1])*sinv;
      w0[2]=b2f(pva[2])*sinv; w0[3]=b2f(pva[3])*sinv;
      w1[0]=b2f(pvb[0])*sinv; w1[1]=b2f(pvb[1])*sinv;
      w1[2]=b2f(pvb[2])*sinv; w1[3]=b2f(pvb[3])*sinv;
      __builtin_nontemporal_store(w0, (f32x4*)&abase[kt*128]);
      __builtin_nontemporal_store(w1, (f32x4*)&abase[kt*128 + 64]);
    }
  }

  // ---------------- end: cross-wave O reduction (once) ----------------
  __syncthreads();                           // all Pt reads done; red may alias
  // O layout per wave: q = qi*16 + g*4 + r, d = db*16 + lane15
  if (wid < 4){
    #pragma unroll
    for (int qi=0;qi<2;++qi)
      #pragma unroll
      for (int db=0;db<4;++db)
        #pragma unroll
        for (int r=0;r<4;++r)
          red[wid*2176 + (qi*16 + g*4 + r)*68 + db*16 + lane15] = o[qi][db][r];
  }
  __syncthreads();
  if (wid >= 4){
    #pragma unroll
    for (int qi=0;qi<2;++qi)
      #pragma unroll
      for (int db=0;db<4;++db)
        #pragma unroll
        for (int r=0;r<4;++r)
          red[(wid-4)*2176 + (qi*16 + g*4 + r)*68 + db*16 + lane15] += o[qi][db][r];
  }
  __syncthreads();
  if (wid < 2){
    for (int j=0; j<32; ++j){
      const int q = (j*64 + lane) >> 6, d = (j*64 + lane) & 63;
      red[wid*2176 + q*68 + d] += red[(wid+2)*2176 + q*68 + d];
    }
  }
  __syncthreads();
  if (wid == 0){
    for (int j=0; j<32; ++j){
      const int q = (j*64 + lane) >> 6, d = (j*64 + lane) & 63;
      red[q*68 + d] += red[2176 + q*68 + d];
    }
  }
  __syncthreads();
  {
    const int b = bh>>3, h = bh&7;
    const int qq = t >> 4, dc = (t & 15)*4;
    const float iv = inv_rs[qq];
    f32x4 vv = *(const f32x4*)&red[qq*68 + dc];
    vv[0]*=iv; vv[1]*=iv; vv[2]*=iv; vv[3]*=iv;
    *(f32x4*)&Og[((size_t)(b*L_ + q0 + qq))*D_ + h*DH_ + dc] = vv;
  }
}

// ---------------------------------------------------------------------------
// Kernel 3: residual add + LayerNorm over d=512 + slice to 508 cols.
// ---------------------------------------------------------------------------
__global__ __launch_bounds__(256) void ln_kernel(
    const float* __restrict__ Og, const float* __restrict__ inp,
    const float* __restrict__ gamma, const float* __restrict__ beta,
    float* __restrict__ out0)
{
  const int row = blockIdx.x, t = threadIdx.x;
  const int lane = t & 63, wid = t >> 6;
  const int c2 = t + 256;
  const float x1 = (t >= 2) ? inp[(size_t)row*DIN + t-2] : 0.f;
  const float x2 = (c2 < 510) ? inp[(size_t)row*DIN + c2-2] : 0.f;
  const float y1 = Og[(size_t)row*D_ + t]  + x1;
  const float y2 = Og[(size_t)row*D_ + c2] + x2;
  float s = y1 + y2, ss = y1*y1 + y2*y2;
  #pragma unroll
  for (int off=1; off<64; off<<=1){
    s  += __shfl_xor(s,  off);
    ss += __shfl_xor(ss, off);
  }
  __shared__ float red[4][2];
  if (lane == 0){ red[wid][0] = s; red[wid][1] = ss; }
  __syncthreads();
  s  = red[0][0]+red[1][0]+red[2][0]+red[3][0];
  ss = red[0][1]+red[1][1]+red[2][1]+red[3][1];
  const float mu   = s * (1.f/512.f);
  const float var  = ss * (1.f/512.f) - mu*mu;
  const float rstd = rsqrtf(var + 1e-6f);
  const float z1 = (y1 - mu)*rstd*gamma[t]  + beta[t];
  const float z2 = (y2 - mu)*rstd*gamma[c2] + beta[c2];
  if (t >= 2)   out0[(size_t)row*DIN + t-2]  = z1;
  if (c2 < 510) out0[(size_t)row*DIN + c2-2] = z2;
}

// ---------------------------------------------------------------------------
extern "C" void kernel_launch(void* const* d_in, const int* in_sizes, int n_in,
                              void* d_out, int out_size, void* d_ws, size_t ws_size,
                              hipStream_t stream) {
  const float* inp   = (const float*)d_in[0];
  const float* Wq    = (const float*)d_in[1];
  const float* Wk    = (const float*)d_in[2];
  const float* Wv    = (const float*)d_in[3];
  const float* gamma = (const float*)d_in[4];
  const float* beta  = (const float*)d_in[5];

  char* ws = (char*)d_ws;
  u16*   Qg = (u16*)(ws);                        // 4 MB
  u16*   Kg = (u16*)(ws + 4194304);              // 4 MB
  u16*   Vt = (u16*)(ws + 8388608);              // 4 MB, transposed [bh][dh][l]
  float* Og = (float*)(ws + 12582912);           // 8 MB (12M..20M)
  u16*   Xb = (u16*)(ws + 12582912);             // 4 MB   (aliases Og: dead
  u16*   Wb = (u16*)(ws + 16777216);             // 1.5 MB  before attn writes)

  float* out0 = (float*)d_out;                   // (2,2048,508)
  float* attn = out0 + 2080768;                  // (2,8,2048,2048)

  cvt_kernel <<<704, 512, 0, stream>>>(inp, Wq, Wk, Wv, Xb, Wb);
  proj_kernel<<<dim3(32,12), 512, 0, stream>>>(Xb, Wb, Qg, Kg, Vt);
  attn_kernel<<<1024, 512, 0, stream>>>(Qg, Kg, Vt, attn, Og);
  ln_kernel  <<<4096, 256, 0, stream>>>(Og, inp, gamma, beta, out0);
}

// Round 8
// 135.721 us; speedup vs baseline: 1.2037x; 1.2037x over previous
//
#include <hip/hip_runtime.h>

typedef short bf16x8 __attribute__((ext_vector_type(8)));
typedef float f32x4 __attribute__((ext_vector_type(4)));
typedef unsigned short u16;
typedef u16 u16x8 __attribute__((ext_vector_type(8)));
typedef u16 u16x4 __attribute__((ext_vector_type(4)));

#define L_ 2048
#define D_ 512
#define H_ 8
#define DH_ 64
#define DIN 508

static __device__ __forceinline__ u16 f2b(float f){
  unsigned u = __builtin_bit_cast(unsigned, f);
  unsigned r = u + 0x7fffu + ((u >> 16) & 1u);   // round-to-nearest-even
  return (u16)(r >> 16);
}
static __device__ __forceinline__ float b2f(u16 u){
  unsigned x = ((unsigned)u) << 16;
  return __builtin_bit_cast(float, x);
}
static __device__ __forceinline__ bf16x8 asbf(u16x8 v){
  return __builtin_bit_cast(bf16x8, v);
}
#define MFMA16(a,b,c) __builtin_amdgcn_mfma_f32_16x16x32_bf16(a,b,c,0,0,0)

// ---------------------------------------------------------------------------
// Kernel 0: one-shot fp32 -> bf16 conversion (+ zero-pad X).
// ---------------------------------------------------------------------------
__global__ __launch_bounds__(512) void cvt_kernel(
    const float* __restrict__ inp, const float* __restrict__ Wq,
    const float* __restrict__ Wk, const float* __restrict__ Wv,
    u16* __restrict__ Xb, u16* __restrict__ Wb)
{
  const int tid = blockIdx.x*512 + threadIdx.x;
  if (tid < 262144) {                       // X part: 4096*512/8 threads
    const int idx8 = tid*8;
    const int row = idx8 >> 9, col = idx8 & 511;
    u16x8 o;
    #pragma unroll
    for (int e=0;e<8;++e){
      const int c = col+e;
      const float v = (c>=2 && c<510) ? inp[(size_t)row*DIN + (c-2)] : 0.f;
      o[e] = f2b(v);
    }
    *(u16x8*)&Xb[idx8] = o;
  } else {                                  // W part: 1536*512/8 threads
    const int idx8 = (tid - 262144)*8;
    const int row = idx8 >> 9, col = idx8 & 511;
    const float* __restrict__ W = (row < 512) ? Wq : (row < 1024) ? Wk : Wv;
    const float* p = &W[(size_t)(row & 511)*D_ + col];
    u16x8 o;
    #pragma unroll
    for (int e=0;e<8;++e) o[e] = f2b(p[e]);
    *(u16x8*)&Wb[idx8] = o;
  }
}

// ---------------------------------------------------------------------------
// Kernel 1: QKV projection, pure-bf16 GEMM.  C[i][n] = sum_k Xb[i][k]*Wb[n][k]
// Q,K stored bf16 as [bh][l][dh]; V stored TRANSPOSED bf16 as [bh][dh][l].
// ---------------------------------------------------------------------------
__global__ __launch_bounds__(512) void proj_kernel(
    const u16* __restrict__ Xb, const u16* __restrict__ Wb,
    u16* __restrict__ Qg, u16* __restrict__ Kg, u16* __restrict__ Vt)
{
  __shared__ u16 Xl[128*72];   // stride 72 u16 = 36dw (== 4 mod 32): conflict-free
  __shared__ u16 Wl[128*72];
  const int t = threadIdx.x;
  const int lane = t & 63, wid = t >> 6;
  const int wr = wid >> 2, wc = wid & 3;          // 2x4 wave grid -> 64x32 per wave
  const int i0 = blockIdx.x * 128;
  const int j0 = blockIdx.y * 128;                // 0..1535
  const int mat = j0 >> 9;                        // 0:Q 1:K 2:V
  const int srow = t >> 3, sc8 = (t & 7) * 8;

  f32x4 acc[4][2];
  #pragma unroll
  for (int a=0;a<4;++a){
    #pragma unroll
    for (int bq=0;bq<2;++bq){ f32x4 z = {0.f,0.f,0.f,0.f}; acc[a][bq] = z; }
  }

  u16x8 xa0 = *(const u16x8*)&Xb[(size_t)(i0+srow)*D_ + sc8];
  u16x8 xa1 = *(const u16x8*)&Xb[(size_t)(i0+64+srow)*D_ + sc8];
  u16x8 wa0 = *(const u16x8*)&Wb[(size_t)(j0+srow)*D_ + sc8];
  u16x8 wa1 = *(const u16x8*)&Wb[(size_t)(j0+64+srow)*D_ + sc8];

  for (int kt=0; kt<8; ++kt){
    __syncthreads();
    *(u16x8*)&Xl[srow*72 + sc8] = xa0;
    *(u16x8*)&Xl[(64+srow)*72 + sc8] = xa1;
    *(u16x8*)&Wl[srow*72 + sc8] = wa0;
    *(u16x8*)&Wl[(64+srow)*72 + sc8] = wa1;
    __syncthreads();
    if (kt < 7){
      const int k1 = (kt+1)*64;
      xa0 = *(const u16x8*)&Xb[(size_t)(i0+srow)*D_ + k1 + sc8];
      xa1 = *(const u16x8*)&Xb[(size_t)(i0+64+srow)*D_ + k1 + sc8];
      wa0 = *(const u16x8*)&Wb[(size_t)(j0+srow)*D_ + k1 + sc8];
      wa1 = *(const u16x8*)&Wb[(size_t)(j0+64+srow)*D_ + k1 + sc8];
    }
    #pragma unroll
    for (int ks=0; ks<2; ++ks){
      const int ko = ks*32 + (lane>>4)*8;
      bf16x8 af[4], bfr[2];
      #pragma unroll
      for (int fm=0; fm<4; ++fm)
        af[fm] = *(const bf16x8*)&Xl[(wr*64 + fm*16 + (lane&15))*72 + ko];
      #pragma unroll
      for (int fn=0; fn<2; ++fn)
        bfr[fn] = *(const bf16x8*)&Wl[(wc*32 + fn*16 + (lane&15))*72 + ko];
      #pragma unroll
      for (int fm=0; fm<4; ++fm){
        #pragma unroll
        for (int fn=0; fn<2; ++fn)
          acc[fm][fn] = MFMA16(af[fm], bfr[fn], acc[fm][fn]);
      }
    }
  }
  #pragma unroll
  for (int fm=0; fm<4; ++fm){
    const int ibase = i0 + wr*64 + fm*16 + (lane>>4)*4;
    const int b = ibase >> 11;
    const int li = ibase & (L_-1);
    #pragma unroll
    for (int fn=0; fn<2; ++fn){
      const int n = j0 + wc*32 + fn*16 + (lane&15);
      const int h = (n>>6) & 7;
      const int dh = n & 63;
      if (mat == 2){
        u16x4 pk;
        #pragma unroll
        for (int r=0;r<4;++r) pk[r] = f2b(acc[fm][fn][r]);
        *(u16x4*)&Vt[((size_t)(b*H_+h)*DH_ + dh)*L_ + li] = pk;   // contiguous in l
      } else {
        u16* dst = ((mat==0)? Qg : Kg) + ((size_t)(b*H_+h)*L_ + li)*DH_ + dh;
        #pragma unroll
        for (int r=0;r<4;++r) dst[(size_t)r*DH_] = f2b(acc[fm][fn][r]);
      }
    }
  }
}

// ---------------------------------------------------------------------------
// Kernel 2a: softmax row sums (pass A standalone). QBLK=64 per block, 8 waves,
// each wave owns a 16-m slice; K fragments direct from L2-resident Kg (no LDS
// staging, no per-tile barriers). Writes inv row sums (1/sum) to rsg.
// S^T form: mfma(K-frag, Q-frag) -> lane holds (m=(lane>>4)*4+r, q=lane&15).
// ---------------------------------------------------------------------------
__global__ __launch_bounds__(512, 4) void rowsum_kernel(
    const u16* __restrict__ Qg, const u16* __restrict__ Kg,
    float* __restrict__ rsg)
{
  __shared__ float rsp[8][64];
  const int t = threadIdx.x, lane = t & 63, wid = t >> 6;
  const int lane15 = lane & 15, g4 = (lane >> 4) * 8;
  const int lin = blockIdx.x;                    // 512 blocks
  const int bh = (lin & 7) + 8*((lin >> 3) & 1);
  const int q0 = (lin >> 4) * 64;
  const u16* Qp = Qg + ((size_t)bh*L_ + q0)*DH_;
  const u16* Kp = Kg + (size_t)bh*L_*DH_;
  const int mrow = wid*16 + lane15;

  bf16x8 qf[4][2];
  #pragma unroll
  for (int qi=0;qi<4;++qi){
    #pragma unroll
    for (int ks=0;ks<2;++ks)
      qf[qi][ks] = *(const bf16x8*)&Qp[(size_t)(qi*16 + lane15)*DH_ + ks*32 + g4];
  }

  float racc[4] = {0.f, 0.f, 0.f, 0.f};
  u16x8 nk0 = *(const u16x8*)&Kp[(size_t)mrow*DH_ + g4];
  u16x8 nk1 = *(const u16x8*)&Kp[(size_t)mrow*DH_ + 32 + g4];
  for (int kt=0; kt<16; ++kt){
    bf16x8 kf0 = asbf(nk0), kf1 = asbf(nk1);
    if (kt < 15){
      nk0 = *(const u16x8*)&Kp[(size_t)((kt+1)*128 + mrow)*DH_ + g4];
      nk1 = *(const u16x8*)&Kp[(size_t)((kt+1)*128 + mrow)*DH_ + 32 + g4];
    }
    #pragma unroll
    for (int qi=0;qi<4;++qi){
      f32x4 s = {0.f,0.f,0.f,0.f};
      s = MFMA16(kf0, qf[qi][0], s);
      s = MFMA16(kf1, qf[qi][1], s);
      #pragma unroll
      for (int r=0;r<4;++r) racc[qi] += __expf(s[r]*0.125f);
    }
  }
  #pragma unroll
  for (int qi=0;qi<4;++qi){
    racc[qi] += __shfl_xor(racc[qi], 16);
    racc[qi] += __shfl_xor(racc[qi], 32);
  }
  if (lane < 16){
    #pragma unroll
    for (int qi=0;qi<4;++qi) rsp[wid][qi*16 + lane] = racc[qi];
  }
  __syncthreads();
  if (t < 64){
    float s = 0.f;
    #pragma unroll
    for (int w=0;w<8;++w) s += rsp[w][t];
    rsg[(size_t)bh*L_ + q0 + t] = 1.f/s;
  }
}

// ---------------------------------------------------------------------------
// Kernel 2b: attn stores + PV (pass B). R6 tile structure (staged Kl/Vl,
// reg-prefetch, 3 barriers/tile, dense nt stores, XCD swizzle) with pass A
// removed -> LDS 44.7 KB -> 3 blocks/CU (24 waves). Reads inv rowsums (rsg).
// ---------------------------------------------------------------------------
__global__ __launch_bounds__(512, 6) void attn_kernel(
    const u16* __restrict__ Qg, const u16* __restrict__ Kg,
    const u16* __restrict__ Vt, const float* __restrict__ rsg,
    float* __restrict__ attn, float* __restrict__ Og)
{
  __shared__ u16 Kl[128*72];     // 18432 B
  __shared__ u16 Vl[64*136];     // 17408 B
  __shared__ u16 Pt[32*136];     //  8704 B
  __shared__ float inv_lds[32];

  const int t = threadIdx.x, lane = t & 63, wid = t >> 6;
  const int lin = blockIdx.x;                    // 1024 blocks
  const int idx = lin >> 3;
  const int bh = (lin & 7) + 8*(idx & 1);
  const int q0 = (idx >> 1) * 32;
  const u16* Qp = Qg + ((size_t)bh*L_ + q0)*DH_;
  const u16* Kp = Kg + (size_t)bh*L_*DH_;
  const u16* Vp = Vt + (size_t)bh*DH_*L_;

  if (t < 32) inv_lds[t] = rsg[(size_t)bh*L_ + q0 + t];

  // Q fragments: rows q = qi*16 + (lane&15), cols k = ks*32 + (lane>>4)*8
  bf16x8 qf[2][2];
  #pragma unroll
  for (int qi=0;qi<2;++qi){
    #pragma unroll
    for (int ks=0;ks<2;++ks)
      qf[qi][ks] = *(const bf16x8*)&Qp[(size_t)(qi*16 + (lane&15))*DH_ + ks*32 + (lane>>4)*8];
  }

  const int kr0 = t>>3, kc8 = (t&7)*8;     // K staging: rows kr0, kr0+64
  const int vr0 = t>>4, vcm = (t&15)*8;    // V staging: rows vr0, vr0+32
  const int g4 = (lane>>4)*8;
  const int mrow = wid*16 + (lane&15);     // this wave's K rows (m slice)

  const int qpv = wid>>2, d0 = (wid&3)*16; // PV: wave owns 16q x 16d frag
  f32x4 o0 = {0.f,0.f,0.f,0.f}, o1 = {0.f,0.f,0.f,0.f};
  const int sr = t >> 4;                   // store: row in tile (0..31)
  const int sc4 = (t & 15) * 4;            // store: col chunk
  float* abase = attn + ((size_t)bh*L_ + q0 + sr)*L_ + sc4;

  u16x8 ka = *(const u16x8*)&Kp[(size_t)kr0*DH_ + kc8];
  u16x8 kb = *(const u16x8*)&Kp[(size_t)(64+kr0)*DH_ + kc8];
  u16x8 va = *(const u16x8*)&Vp[(size_t)vr0*L_ + vcm];
  u16x8 vb = *(const u16x8*)&Vp[(size_t)(32+vr0)*L_ + vcm];

  __syncthreads();                          // inv_lds visible
  const float sinv = inv_lds[sr];

  for (int kt=0; kt<16; ++kt){
    __syncthreads();                         // Pt/Vl consumers of prev tile done
    *(u16x8*)&Kl[kr0*72 + kc8] = ka;
    *(u16x8*)&Kl[(64+kr0)*72 + kc8] = kb;
    *(u16x8*)&Vl[vr0*136 + vcm] = va;
    *(u16x8*)&Vl[(32+vr0)*136 + vcm] = vb;
    __syncthreads();
    if (kt < 15){
      ka = *(const u16x8*)&Kp[(size_t)((kt+1)*128 + kr0)*DH_ + kc8];
      kb = *(const u16x8*)&Kp[(size_t)((kt+1)*128 + 64 + kr0)*DH_ + kc8];
      va = *(const u16x8*)&Vp[(size_t)vr0*L_ + (kt+1)*128 + vcm];
      vb = *(const u16x8*)&Vp[(size_t)(32+vr0)*L_ + (kt+1)*128 + vcm];
    }
    bf16x8 kf0 = *(const bf16x8*)&Kl[mrow*72 + g4];
    bf16x8 kf1 = *(const bf16x8*)&Kl[mrow*72 + 32 + g4];
    f32x4 s0 = {0.f,0.f,0.f,0.f}, s1 = {0.f,0.f,0.f,0.f};
    s0 = MFMA16(kf0, qf[0][0], s0); s0 = MFMA16(kf1, qf[0][1], s0);
    s1 = MFMA16(kf0, qf[1][0], s1); s1 = MFMA16(kf1, qf[1][1], s1);
    u16x4 p0, p1;
    p0[0] = f2b(__expf(s0[0]*0.125f)); p0[1] = f2b(__expf(s0[1]*0.125f));
    p0[2] = f2b(__expf(s0[2]*0.125f)); p0[3] = f2b(__expf(s0[3]*0.125f));
    p1[0] = f2b(__expf(s1[0]*0.125f)); p1[1] = f2b(__expf(s1[1]*0.125f));
    p1[2] = f2b(__expf(s1[2]*0.125f)); p1[3] = f2b(__expf(s1[3]*0.125f));
    *(u16x4*)&Pt[(lane&15)*136 + wid*16 + (lane>>4)*4] = p0;
    *(u16x4*)&Pt[(16 + (lane&15))*136 + wid*16 + (lane>>4)*4] = p1;
    __syncthreads();                         // Pt/Vl ready
    // DENSE normalized attn store: 16 lanes cover 256 B contiguous per instr
    {
      const u16x4 pva = *(const u16x4*)&Pt[sr*136 + sc4];
      const u16x4 pvb = *(const u16x4*)&Pt[sr*136 + 64 + sc4];
      f32x4 w0, w1;
      w0[0]=b2f(pva[0])*sinv; w0[1]=b2f(pva[1])*sinv;
      w0[2]=b2f(pva[2])*sinv; w0[3]=b2f(pva[3])*sinv;
      w1[0]=b2f(pvb[0])*sinv; w1[1]=b2f(pvb[1])*sinv;
      w1[2]=b2f(pvb[2])*sinv; w1[3]=b2f(pvb[3])*sinv;
      __builtin_nontemporal_store(w0, (f32x4*)&abase[kt*128]);
      __builtin_nontemporal_store(w1, (f32x4*)&abase[kt*128 + 64]);
    }
    #pragma unroll
    for (int ms=0; ms<4; ++ms){
      bf16x8 pa = *(const bf16x8*)&Pt[(qpv*16 + (lane&15))*136 + ms*32 + g4];
      bf16x8 vv = *(const bf16x8*)&Vl[(d0 + (lane&15))*136 + ms*32 + g4];
      if (ms&1) o1 = MFMA16(pa, vv, o1); else o0 = MFMA16(pa, vv, o0);
    }
  }
  {
    const int b = bh>>3, h = bh&7;
    #pragma unroll
    for (int r=0;r<4;++r){
      const int qr = qpv*16 + (lane>>4)*4 + r;
      Og[((size_t)(b*L_ + q0 + qr))*D_ + h*DH_ + d0 + (lane&15)] = (o0[r]+o1[r])*inv_lds[qr];
    }
  }
}

// ---------------------------------------------------------------------------
// Kernel 3: residual add + LayerNorm over d=512 + slice to 508 cols.
// ---------------------------------------------------------------------------
__global__ __launch_bounds__(256) void ln_kernel(
    const float* __restrict__ Og, const float* __restrict__ inp,
    const float* __restrict__ gamma, const float* __restrict__ beta,
    float* __restrict__ out0)
{
  const int row = blockIdx.x, t = threadIdx.x;
  const int lane = t & 63, wid = t >> 6;
  const int c2 = t + 256;
  const float x1 = (t >= 2) ? inp[(size_t)row*DIN + t-2] : 0.f;
  const float x2 = (c2 < 510) ? inp[(size_t)row*DIN + c2-2] : 0.f;
  const float y1 = Og[(size_t)row*D_ + t]  + x1;
  const float y2 = Og[(size_t)row*D_ + c2] + x2;
  float s = y1 + y2, ss = y1*y1 + y2*y2;
  #pragma unroll
  for (int off=1; off<64; off<<=1){
    s  += __shfl_xor(s,  off);
    ss += __shfl_xor(ss, off);
  }
  __shared__ float red[4][2];
  if (lane == 0){ red[wid][0] = s; red[wid][1] = ss; }
  __syncthreads();
  s  = red[0][0]+red[1][0]+red[2][0]+red[3][0];
  ss = red[0][1]+red[1][1]+red[2][1]+red[3][1];
  const float mu   = s * (1.f/512.f);
  const float var  = ss * (1.f/512.f) - mu*mu;
  const float rstd = rsqrtf(var + 1e-6f);
  const float z1 = (y1 - mu)*rstd*gamma[t]  + beta[t];
  const float z2 = (y2 - mu)*rstd*gamma[c2] + beta[c2];
  if (t >= 2)   out0[(size_t)row*DIN + t-2]  = z1;
  if (c2 < 510) out0[(size_t)row*DIN + c2-2] = z2;
}

// ---------------------------------------------------------------------------
extern "C" void kernel_launch(void* const* d_in, const int* in_sizes, int n_in,
                              void* d_out, int out_size, void* d_ws, size_t ws_size,
                              hipStream_t stream) {
  const float* inp   = (const float*)d_in[0];
  const float* Wq    = (const float*)d_in[1];
  const float* Wk    = (const float*)d_in[2];
  const float* Wv    = (const float*)d_in[3];
  const float* gamma = (const float*)d_in[4];
  const float* beta  = (const float*)d_in[5];

  char* ws = (char*)d_ws;
  u16*   Qg  = (u16*)(ws);                       // 4 MB
  u16*   Kg  = (u16*)(ws + 4194304);             // 4 MB
  u16*   Vt  = (u16*)(ws + 8388608);             // 4 MB, transposed [bh][dh][l]
  float* Og  = (float*)(ws + 12582912);          // 8 MB (12M..20M)
  u16*   Xb  = (u16*)(ws + 12582912);            // 4 MB   (aliases Og: dead
  u16*   Wb  = (u16*)(ws + 16777216);            // 1.5 MB  before attn writes)
  float* rsg = (float*)(ws + 20971520);          // 128 KB inv row sums

  float* out0 = (float*)d_out;                   // (2,2048,508)
  float* attn = out0 + 2080768;                  // (2,8,2048,2048)

  cvt_kernel   <<<704, 512, 0, stream>>>(inp, Wq, Wk, Wv, Xb, Wb);
  proj_kernel  <<<dim3(32,12), 512, 0, stream>>>(Xb, Wb, Qg, Kg, Vt);
  rowsum_kernel<<<512, 512, 0, stream>>>(Qg, Kg, rsg);
  attn_kernel  <<<1024, 512, 0, stream>>>(Qg, Kg, Vt, rsg, attn, Og);
  ln_kernel    <<<4096, 256, 0, stream>>>(Og, inp, gamma, beta, out0);
}